// Round 9
// baseline (56.125 us; speedup 1.0000x reference)
//
#include <hip/hip_runtime.h>

#define B_ 8
#define T_ 2048
#define V_ 256
#define D_ 512
#define LEFT_ 16
#define TPW 2                       // tokens per wave, processed sequentially
#define NRW (TPW + LEFT_ - 1)       // 17 window rows per wave

__device__ __forceinline__ constexpr int rev4(int x) {
    return (((x >> 0) & 1) << 3) | (((x >> 1) & 1) << 2) |
           (((x >> 2) & 1) << 1) | (((x >> 3) & 1) << 0);
}

__device__ __forceinline__ float dot8(const float4& m0, const float4& m1,
                                      const float4& e0, const float4& e1) {
    return m0.x * e0.x + m0.y * e0.y + m0.z * e0.z + m0.w * e0.w
         + m1.x * e1.x + m1.y * e1.y + m1.z * e1.z + m1.w * e1.w;
}

__global__ __launch_bounds__(256)
void attn_cell_kernel(const int* __restrict__ symbols,
                      const float* __restrict__ encodings,
                      const float* __restrict__ M,
                      const float* __restrict__ C,
                      float* __restrict__ out,      // (B,T,1024)
                      float* __restrict__ p_out) {  // (B,T,16)
    const int tid  = threadIdx.x;
    const int lane = tid & 63;
    const int w    = tid >> 6;

    const int blk = blockIdx.x;
    const int b   = blk >> 8;                        // 256 blocks per batch row
    const int tw  = (blk & 255) * (4 * TPW) + w * TPW;  // wave's first token
    const int* symrow = symbols + b * T_;
    const size_t rowbase = (size_t)b * T_ + tw;
    const int dof = lane * 8;

    // window symbols -> SGPRs (wave-uniform)
    int syms[NRW];
    #pragma unroll
    for (int i = 0; i < NRW; ++i) {
        int pos = tw - (LEFT_ - 1) + i;
        pos = max(pos, 0);
        syms[i] = __builtin_amdgcn_readfirstlane(symrow[pos]);
    }

    #pragma unroll
    for (int tk = 0; tk < TPW; ++tk) {
        const float* e = encodings + (rowbase + tk) * D_ + dof;
        const float4 e0 = *(const float4*)e;
        const float4 e1 = *(const float4*)(e + 4);

        // ---- 16 per-lane partial scores (one per history slot) ----
        float s[16];
        #pragma unroll
        for (int l = 0; l < 16; ++l) {
            const float* mr = M + (size_t)syms[tk + l] * D_ + dof;
            const float4 m0 = *(const float4*)mr;
            const float4 m1 = *(const float4*)(mr + 4);
            s[l] = dot8(m0, m1, e0, e1);
        }

        // ---- folding butterfly: 15 shfl, 16 values -> 1 per lane (slot = rev4(lane&15)) ----
        #pragma unroll
        for (int k = 0; k < 8; ++k) {
            const float lo = s[k], hi = s[k + 8];
            const float sd = (lane & 1) ? lo : hi;
            const float rv = __shfl_xor(sd, 1);
            s[k] = (lane & 1) ? hi + rv : lo + rv;
        }
        #pragma unroll
        for (int k = 0; k < 4; ++k) {
            const float lo = s[k], hi = s[k + 4];
            const float sd = (lane & 2) ? lo : hi;
            const float rv = __shfl_xor(sd, 2);
            s[k] = (lane & 2) ? hi + rv : lo + rv;
        }
        #pragma unroll
        for (int k = 0; k < 2; ++k) {
            const float lo = s[k], hi = s[k + 2];
            const float sd = (lane & 4) ? lo : hi;
            const float rv = __shfl_xor(sd, 4);
            s[k] = (lane & 4) ? hi + rv : lo + rv;
        }
        {
            const float lo = s[0], hi = s[1];
            const float sd = (lane & 8) ? lo : hi;
            const float rv = __shfl_xor(sd, 8);
            s[0] = (lane & 8) ? hi + rv : lo + rv;
        }
        float v = s[0];
        v += __shfl_xor(v, 16);
        v += __shfl_xor(v, 32);
        // lane holds the full score for slot rl = rev4(lane&15)

        // ---- softmax over the 16-lane group ----
        float mx = v;
        mx = fmaxf(mx, __shfl_xor(mx, 1));
        mx = fmaxf(mx, __shfl_xor(mx, 2));
        mx = fmaxf(mx, __shfl_xor(mx, 4));
        mx = fmaxf(mx, __shfl_xor(mx, 8));
        const float ex = __expf(v - mx);
        float sum = ex;
        sum += __shfl_xor(sum, 1);
        sum += __shfl_xor(sum, 2);
        sum += __shfl_xor(sum, 4);
        sum += __shfl_xor(sum, 8);
        const float p = ex / sum;

        if (lane < 16)
            p_out[(rowbase + tk) * 16 + rev4(lane)] = p;

        // ---- compressed = sum_l p_l * C_row_l (p via const-lane broadcast) ----
        float4 a0 = make_float4(0.f, 0.f, 0.f, 0.f);
        float4 a1 = make_float4(0.f, 0.f, 0.f, 0.f);
        #pragma unroll
        for (int l = 0; l < 16; ++l) {
            const float* cr = C + (size_t)syms[tk + l] * D_ + dof;
            const float4 c0 = *(const float4*)cr;
            const float4 c1 = *(const float4*)(cr + 4);
            const float pb = __shfl(p, rev4(l));    // lane rev4(l) owns slot l
            a0.x += pb * c0.x; a0.y += pb * c0.y; a0.z += pb * c0.z; a0.w += pb * c0.w;
            a1.x += pb * c1.x; a1.y += pb * c1.y; a1.z += pb * c1.z; a1.w += pb * c1.w;
        }

        float* ob = out + (rowbase + tk) * 1024 + dof;
        *(float4*)ob            = a0;
        *(float4*)(ob + 4)      = a1;
        *(float4*)(ob + D_)     = e0;   // exact f32 enc passthrough
        *(float4*)(ob + D_ + 4) = e1;
    }
}

extern "C" void kernel_launch(void* const* d_in, const int* in_sizes, int n_in,
                              void* d_out, int out_size, void* d_ws, size_t ws_size,
                              hipStream_t stream) {
    const int*   symbols   = (const int*)d_in[0];
    const float* encodings = (const float*)d_in[1];
    const float* M         = (const float*)d_in[2];
    const float* C         = (const float*)d_in[3];
    float* out   = (float*)d_out;
    float* p_out = out + (size_t)B_ * T_ * 1024;   // concat order: output, then p

    dim3 grid(B_ * (T_ / (4 * TPW)));              // 2048 blocks, 8 tokens each
    attn_cell_kernel<<<grid, 256, 0, stream>>>(symbols, encodings, M, C, out, p_out);
}

// Round 10
// 43.560 us; speedup vs baseline: 1.2885x; 1.2885x over previous
//
#include <hip/hip_runtime.h>
#include <hip/hip_bf16.h>

#define B_ 8
#define T_ 2048
#define V_ 256
#define D_ 512
#define LEFT_ 16

typedef float f32x4 __attribute__((ext_vector_type(4)));
typedef short bf16x8 __attribute__((ext_vector_type(8)));
union FragU { unsigned u[4]; bf16x8 v; };

__device__ __forceinline__ unsigned pack_bf2(float a, float b) {
    __hip_bfloat162 h = __float22bfloat162_rn(make_float2(a, b));
    union { __hip_bfloat162 h; unsigned u; } c; c.h = h; return c.u;
}

// Block = 16 tokens, 8 waves.
// Phase A: S_ext[j=0..31][t=0..15] = sum_k M[sym[j]][k] * E[t][k], K split 64/wave.
//   Fragment maps (verified in R7): A/B: row(col)=lane&15, k=4*(lane>>4)+(e&3)+16*(e>>2);
//   D: col=lane&15, row=4*(lane>>4)+r.
// After reduce, lane (q,t) holds S[j=4q+r+16g][t] -> masked softmax (band j-t in [0,16))
// -> p lands exactly where phase B's B-fragment needs it (k=j map identical). No shuffle.
// Phase B: compressed^T[d][t] = sum_j C[sym[j]][d] * P_ext[t][j], 1 MFMA per 16-d chunk.
__global__ __launch_bounds__(512)
void attn_cell_kernel(const int* __restrict__ symbols,
                      const float* __restrict__ encodings,
                      const float* __restrict__ M,
                      const float* __restrict__ C,
                      float* __restrict__ out,      // (B,T,1024)
                      float* __restrict__ p_out) {  // (B,T,16)
    __shared__ float spart[8][16][36];   // [wave][t][j 0..31, pad 36] = 18 KB

    const int tid  = threadIdx.x;
    const int lane = tid & 63;
    const int w    = tid >> 6;      // 0..7
    const int q    = lane >> 4;     // 0..3
    const int t    = lane & 15;     // token slot / fragment row index

    const int blk = blockIdx.x;
    const int b   = blk >> 7;
    const int t0  = (blk & 127) * 16;
    const int* symrow = symbols + b * T_;
    const size_t rowbase = (size_t)b * T_ + t0;

    // ---- enc passthrough: 16 rows x 512 f32, 512 threads x 16 f32, coalesced ----
    {
        const int row = tid >> 5;           // 32 threads per row
        const int c0  = (tid & 31) * 16;
        const float* src = encodings + (rowbase + row) * D_ + c0;
        float* dst = out + (rowbase + row) * 1024 + D_ + c0;
        #pragma unroll
        for (int kk = 0; kk < 4; ++kk)
            ((float4*)dst)[kk] = ((const float4*)src)[kk];
    }

    // per-lane symbols: phase A rows j = t + 16g
    int sa[2];
    #pragma unroll
    for (int g = 0; g < 2; ++g) {
        int pos = t0 + t + 16 * g - (LEFT_ - 1);
        pos = max(pos, 0); pos = min(pos, T_ - 1);
        sa[g] = symrow[pos];
    }
    // per-lane symbols: phase B k-elems j(e) = 4q + (e&3) + 16*(e>>2)
    int sb[8];
    #pragma unroll
    for (int e = 0; e < 8; ++e) {
        int j = 4 * q + (e & 3) + 16 * (e >> 2);
        int pos = t0 + j - (LEFT_ - 1);
        pos = max(pos, 0); pos = min(pos, T_ - 1);
        sb[e] = symrow[pos];
    }

    // ---- phase A: partial scores over k in [64w, 64w+64) ----
    f32x4 acc0 = {0.f, 0.f, 0.f, 0.f}, acc1 = {0.f, 0.f, 0.f, 0.f};
    #pragma unroll
    for (int kc = 0; kc < 2; ++kc) {
        const int k0 = w * 64 + kc * 32 + 4 * q;
        const float* eb = encodings + (rowbase + t) * D_ + k0;
        const float4 b0 = *(const float4*)eb;
        const float4 b1 = *(const float4*)(eb + 16);
        FragU bf;
        bf.u[0] = pack_bf2(b0.x, b0.y); bf.u[1] = pack_bf2(b0.z, b0.w);
        bf.u[2] = pack_bf2(b1.x, b1.y); bf.u[3] = pack_bf2(b1.z, b1.w);
        {
            const float* ma = M + (size_t)sa[0] * D_ + k0;
            const float4 a0 = *(const float4*)ma;
            const float4 a1 = *(const float4*)(ma + 16);
            FragU af;
            af.u[0] = pack_bf2(a0.x, a0.y); af.u[1] = pack_bf2(a0.z, a0.w);
            af.u[2] = pack_bf2(a1.x, a1.y); af.u[3] = pack_bf2(a1.z, a1.w);
            acc0 = __builtin_amdgcn_mfma_f32_16x16x32_bf16(af.v, bf.v, acc0, 0, 0, 0);
        }
        {
            const float* ma = M + (size_t)sa[1] * D_ + k0;
            const float4 a0 = *(const float4*)ma;
            const float4 a1 = *(const float4*)(ma + 4);
            const float4 a1b = *(const float4*)(ma + 16);
            FragU af;
            af.u[0] = pack_bf2(a0.x, a0.y); af.u[1] = pack_bf2(a0.z, a0.w);
            af.u[2] = pack_bf2(a1b.x, a1b.y); af.u[3] = pack_bf2(a1b.z, a1b.w);
            (void)a1;
            acc1 = __builtin_amdgcn_mfma_f32_16x16x32_bf16(af.v, bf.v, acc1, 0, 0, 0);
        }
    }
    *(f32x4*)&spart[w][t][4 * q]      = acc0;   // j = 4q+r
    *(f32x4*)&spart[w][t][16 + 4 * q] = acc1;   // j = 16+4q+r
    __syncthreads();

    // ---- reduce the 8 wave-slices: lane (q,t) owns j = 4q+r (+16) ----
    f32x4 s0 = *(const f32x4*)&spart[0][t][4 * q];
    f32x4 s1 = *(const f32x4*)&spart[0][t][16 + 4 * q];
    #pragma unroll
    for (int w2 = 1; w2 < 8; ++w2) {
        s0 += *(const f32x4*)&spart[w2][t][4 * q];
        s1 += *(const f32x4*)&spart[w2][t][16 + 4 * q];
    }

    // ---- masked softmax over the band j - t in [0,16) ----
    float mx = -3.0e38f;
    #pragma unroll
    for (int r = 0; r < 4; ++r) {
        if ((unsigned)(4 * q + r - t) < 16u)      mx = fmaxf(mx, s0[r]);
        if ((unsigned)(4 * q + r + 16 - t) < 16u) mx = fmaxf(mx, s1[r]);
    }
    mx = fmaxf(mx, __shfl_xor(mx, 16));
    mx = fmaxf(mx, __shfl_xor(mx, 32));
    float p0[4], p1[4];
    float sum = 0.f;
    #pragma unroll
    for (int r = 0; r < 4; ++r) {
        const bool m0 = (unsigned)(4 * q + r - t) < 16u;
        const bool m1 = (unsigned)(4 * q + r + 16 - t) < 16u;
        p0[r] = m0 ? __expf(s0[r] - mx) : 0.f;
        p1[r] = m1 ? __expf(s1[r] - mx) : 0.f;
        sum += p0[r] + p1[r];
    }
    sum += __shfl_xor(sum, 16);
    sum += __shfl_xor(sum, 32);
    const float inv = 1.f / sum;
    #pragma unroll
    for (int r = 0; r < 4; ++r) { p0[r] *= inv; p1[r] *= inv; }

    // p_out: each (q,t) lane owns exactly one of {j, j+16} per r (wave 0 only)
    if (w == 0) {
        #pragma unroll
        for (int r = 0; r < 4; ++r) {
            const int j0 = 4 * q + r;
            if ((unsigned)(j0 - t) < 16u)
                p_out[(rowbase + t) * 16 + (j0 - t)] = p0[r];
            else
                p_out[(rowbase + t) * 16 + (j0 + 16 - t)] = p1[r];
        }
    }

    // pack P_ext into the phase-B B-fragment (elements already lane-correct)
    FragU pf;
    pf.u[0] = pack_bf2(p0[0], p0[1]); pf.u[1] = pack_bf2(p0[2], p0[3]);
    pf.u[2] = pack_bf2(p1[0], p1[1]); pf.u[3] = pack_bf2(p1[2], p1[3]);

    // ---- phase B: wave owns d in [64w, 64w+64), 4 MFMAs ----
    #pragma unroll
    for (int m = 0; m < 4; ++m) {
        const int dc = w * 4 + m;
        const int dA = dc * 16 + t;         // A-fragment row = d within tile
        float c[8];
        #pragma unroll
        for (int e = 0; e < 8; ++e)
            c[e] = C[(size_t)sb[e] * D_ + dA];
        FragU af;
        af.u[0] = pack_bf2(c[0], c[1]); af.u[1] = pack_bf2(c[2], c[3]);
        af.u[2] = pack_bf2(c[4], c[5]); af.u[3] = pack_bf2(c[6], c[7]);
        f32x4 o = {0.f, 0.f, 0.f, 0.f};
        o = __builtin_amdgcn_mfma_f32_16x16x32_bf16(af.v, pf.v, o, 0, 0, 0);
        float* ob = out + (rowbase + t) * 1024 + dc * 16 + 4 * q;
        *(float4*)ob = make_float4(o[0], o[1], o[2], o[3]);
    }
}

extern "C" void kernel_launch(void* const* d_in, const int* in_sizes, int n_in,
                              void* d_out, int out_size, void* d_ws, size_t ws_size,
                              hipStream_t stream) {
    const int*   symbols   = (const int*)d_in[0];
    const float* encodings = (const float*)d_in[1];
    const float* M         = (const float*)d_in[2];
    const float* C         = (const float*)d_in[3];
    float* out   = (float*)d_out;
    float* p_out = out + (size_t)B_ * T_ * 1024;   // concat order: output, then p

    dim3 grid(B_ * (T_ / 16));                     // 1024 blocks x 512 threads
    attn_cell_kernel<<<grid, 512, 0, stream>>>(symbols, encodings, M, C, out, p_out);
}

// Round 11
// 32.877 us; speedup vs baseline: 1.7071x; 1.3249x over previous
//
#include <hip/hip_runtime.h>
#include <hip/hip_bf16.h>

#define B_ 8
#define T_ 2048
#define V_ 256
#define D_ 512
#define LEFT_ 16
#define C_LDW 520                    // padded bf16 row width for staged C

typedef float f32x4 __attribute__((ext_vector_type(4)));
typedef short bf16x8 __attribute__((ext_vector_type(8)));
typedef unsigned long long u64;
union FragU { unsigned u[4]; u64 ull[2]; bf16x8 v; };

__device__ __forceinline__ unsigned pack_bf2(float a, float b) {
    __hip_bfloat162 h = __float22bfloat162_rn(make_float2(a, b));
    union { __hip_bfloat162 h; unsigned u; } c; c.h = h; return c.u;
}

// LDS: [0, 33280)  M bf16 [32][512] swizzled (phase A) / C bf16 [32][520] (phase B)
//      [33280, 51712)  spart f32 [8][16][36]
#define SPART_OFF 33280
#define SMEM_BYTES (SPART_OFF + 8 * 16 * 36 * 4)

__global__ __launch_bounds__(512)
void attn_cell_kernel(const int* __restrict__ symbols,
                      const float* __restrict__ encodings,
                      const float* __restrict__ M,
                      const float* __restrict__ C,
                      float* __restrict__ out,      // (B,T,1024)
                      float* __restrict__ p_out) {  // (B,T,16)
    __shared__ __align__(16) char smem[SMEM_BYTES];

    const int tid  = threadIdx.x;
    const int lane = tid & 63;
    const int w    = tid >> 6;      // 0..7
    const int q    = lane >> 4;     // 0..3
    const int t    = lane & 15;

    const int blk = blockIdx.x;
    const int b   = blk >> 7;
    const int t0  = (blk & 127) * 16;
    const int* symrow = symbols + b * T_;
    const size_t rowbase = (size_t)b * T_ + t0;

    // ---- stage M: [32][512] bf16, 8B granules XOR-swizzled by (row&7) ----
    {
        u64* r8 = (u64*)smem;
        #pragma unroll
        for (int i = tid; i < 2048; i += 512) {
            const int j = i >> 6;
            const int g = i & 63;          // 16B source granule (8 f32)
            int pos = t0 - (LEFT_ - 1) + j;
            pos = max(pos, 0); pos = min(pos, T_ - 1);
            const float* src = M + (size_t)symrow[pos] * D_ + g * 8;
            const float4 v0 = ((const float4*)src)[0];
            const float4 v1 = ((const float4*)src)[1];
            const u64 lo = (u64)pack_bf2(v0.x, v0.y) | ((u64)pack_bf2(v0.z, v0.w) << 32);
            const u64 hi = (u64)pack_bf2(v1.x, v1.y) | ((u64)pack_bf2(v1.z, v1.w) << 32);
            const int c = j & 7;
            r8[j * 128 + ((2 * g) ^ c)]     = lo;
            r8[j * 128 + ((2 * g + 1) ^ c)] = hi;
        }
    }
    __syncthreads();

    // ---- phase A: S_ext partials, K in [64w, 64w+64); enc load fused with passthrough ----
    f32x4 acc0 = {0.f, 0.f, 0.f, 0.f}, acc1 = {0.f, 0.f, 0.f, 0.f};
    {
        const float* ebase = encodings + (rowbase + t) * D_;
        float* obase = out + (rowbase + t) * 1024 + D_;
        const u64* r8 = (const u64*)smem;
        const int c0 = t & 7;              // == (t+16)&7
        #pragma unroll
        for (int kc = 0; kc < 2; ++kc) {
            const int d0 = 64 * w + 32 * kc + 4 * q;
            const float4 e0 = *(const float4*)(ebase + d0);
            const float4 e1 = *(const float4*)(ebase + d0 + 16);
            *(float4*)(obase + d0)      = e0;   // exact f32 enc passthrough
            *(float4*)(obase + d0 + 16) = e1;
            FragU bf;
            bf.u[0] = pack_bf2(e0.x, e0.y); bf.u[1] = pack_bf2(e0.z, e0.w);
            bf.u[2] = pack_bf2(e1.x, e1.y); bf.u[3] = pack_bf2(e1.z, e1.w);
            const int gb = 16 * w + 8 * kc + q;  // 8B-granule base (k-offset 4q)
            FragU a0, a1;
            a0.ull[0] = r8[t * 128        + ((gb)     ^ c0)];
            a0.ull[1] = r8[t * 128        + ((gb + 4) ^ c0)];
            a1.ull[0] = r8[(t + 16) * 128 + ((gb)     ^ c0)];
            a1.ull[1] = r8[(t + 16) * 128 + ((gb + 4) ^ c0)];
            acc0 = __builtin_amdgcn_mfma_f32_16x16x32_bf16(a0.v, bf.v, acc0, 0, 0, 0);
            acc1 = __builtin_amdgcn_mfma_f32_16x16x32_bf16(a1.v, bf.v, acc1, 0, 0, 0);
        }
    }
    {
        float* sp = (float*)(smem + SPART_OFF);
        *(f32x4*)&sp[(w * 16 + t) * 36 + 4 * q]      = acc0;  // j = 4q+r
        *(f32x4*)&sp[(w * 16 + t) * 36 + 16 + 4 * q] = acc1;  // j = 16+4q+r
    }
    __syncthreads();

    // ---- reduce 8 slices; masked softmax; in-lane p handoff (R10-verified) ----
    FragU pf;
    {
        const float* sp = (const float*)(smem + SPART_OFF);
        f32x4 s0 = *(const f32x4*)&sp[t * 36 + 4 * q];
        f32x4 s1 = *(const f32x4*)&sp[t * 36 + 16 + 4 * q];
        #pragma unroll
        for (int w2 = 1; w2 < 8; ++w2) {
            s0 += *(const f32x4*)&sp[(w2 * 16 + t) * 36 + 4 * q];
            s1 += *(const f32x4*)&sp[(w2 * 16 + t) * 36 + 16 + 4 * q];
        }
        float mx = -3.0e38f;
        #pragma unroll
        for (int r = 0; r < 4; ++r) {
            if ((unsigned)(4 * q + r - t) < 16u)      mx = fmaxf(mx, s0[r]);
            if ((unsigned)(4 * q + r + 16 - t) < 16u) mx = fmaxf(mx, s1[r]);
        }
        mx = fmaxf(mx, __shfl_xor(mx, 16));
        mx = fmaxf(mx, __shfl_xor(mx, 32));
        float p0[4], p1[4];
        float sum = 0.f;
        #pragma unroll
        for (int r = 0; r < 4; ++r) {
            const bool m0 = (unsigned)(4 * q + r - t) < 16u;
            const bool m1 = (unsigned)(4 * q + r + 16 - t) < 16u;
            p0[r] = m0 ? __expf(s0[r] - mx) : 0.f;
            p1[r] = m1 ? __expf(s1[r] - mx) : 0.f;
            sum += p0[r] + p1[r];
        }
        sum += __shfl_xor(sum, 16);
        sum += __shfl_xor(sum, 32);
        const float inv = 1.f / sum;
        #pragma unroll
        for (int r = 0; r < 4; ++r) { p0[r] *= inv; p1[r] *= inv; }

        if (w == 0) {
            #pragma unroll
            for (int r = 0; r < 4; ++r) {
                const int j0 = 4 * q + r;
                if ((unsigned)(j0 - t) < 16u)
                    p_out[(rowbase + t) * 16 + (j0 - t)] = p0[r];
                else
                    p_out[(rowbase + t) * 16 + (j0 + 16 - t)] = p1[r];
            }
        }
        pf.u[0] = pack_bf2(p0[0], p0[1]); pf.u[1] = pack_bf2(p0[2], p0[3]);
        pf.u[2] = pack_bf2(p1[0], p1[1]); pf.u[3] = pack_bf2(p1[2], p1[3]);
    }
    __syncthreads();

    // ---- stage C: [32][520] bf16 rows (row-major, padded) into the M buffer ----
    {
        #pragma unroll
        for (int i = tid; i < 2048; i += 512) {
            const int j = i >> 6;
            const int g = i & 63;
            int pos = t0 - (LEFT_ - 1) + j;
            pos = max(pos, 0); pos = min(pos, T_ - 1);
            const float* src = C + (size_t)symrow[pos] * D_ + g * 8;
            const float4 v0 = ((const float4*)src)[0];
            const float4 v1 = ((const float4*)src)[1];
            u64* dst = (u64*)(smem + ((size_t)j * C_LDW + g * 8) * 2);
            dst[0] = (u64)pack_bf2(v0.x, v0.y) | ((u64)pack_bf2(v0.z, v0.w) << 32);
            dst[1] = (u64)pack_bf2(v1.x, v1.y) | ((u64)pack_bf2(v1.z, v1.w) << 32);
        }
    }
    __syncthreads();

    // ---- phase B: O^T tile = C^T · P^T; A-frags via ds_read_u16 from row-major C ----
    {
        const unsigned short* cb = (const unsigned short*)smem;
        #pragma unroll
        for (int m = 0; m < 4; ++m) {
            const int dc = w * 4 + m;           // d-chunk 0..31
            const int dA = dc * 16 + t;         // d_low = lane&15
            unsigned short cbits[8];
            #pragma unroll
            for (int e = 0; e < 8; ++e) {
                const int j = 4 * q + (e & 3) + 16 * (e >> 2);
                cbits[e] = cb[j * C_LDW + dA];
            }
            FragU af;
            af.u[0] = cbits[0] | ((unsigned)cbits[1] << 16);
            af.u[1] = cbits[2] | ((unsigned)cbits[3] << 16);
            af.u[2] = cbits[4] | ((unsigned)cbits[5] << 16);
            af.u[3] = cbits[6] | ((unsigned)cbits[7] << 16);
            f32x4 o = {0.f, 0.f, 0.f, 0.f};
            o = __builtin_amdgcn_mfma_f32_16x16x32_bf16(af.v, pf.v, o, 0, 0, 0);
            float* ob = out + (rowbase + t) * 1024 + dc * 16 + 4 * q;
            *(float4*)ob = make_float4(o[0], o[1], o[2], o[3]);
        }
    }
}

extern "C" void kernel_launch(void* const* d_in, const int* in_sizes, int n_in,
                              void* d_out, int out_size, void* d_ws, size_t ws_size,
                              hipStream_t stream) {
    const int*   symbols   = (const int*)d_in[0];
    const float* encodings = (const float*)d_in[1];
    const float* M         = (const float*)d_in[2];
    const float* C         = (const float*)d_in[3];
    float* out   = (float*)d_out;
    float* p_out = out + (size_t)B_ * T_ * 1024;   // concat order: output, then p

    dim3 grid(B_ * (T_ / 16));                     // 1024 blocks x 512 threads
    attn_cell_kernel<<<grid, 512, 0, stream>>>(symbols, encodings, M, C, out, p_out);
}

// Round 12
// 32.094 us; speedup vs baseline: 1.7488x; 1.0244x over previous
//
#include <hip/hip_runtime.h>
#include <hip/hip_bf16.h>

#define B_ 8
#define T_ 2048
#define V_ 256
#define D_ 512
#define LEFT_ 16
#define C_LDW 520                    // padded bf16 row width for staged C

typedef float f32x4 __attribute__((ext_vector_type(4)));
typedef short bf16x8 __attribute__((ext_vector_type(8)));
typedef unsigned long long u64;
union FragU { unsigned u[4]; u64 ull[2]; bf16x8 v; };

__device__ __forceinline__ unsigned pack_bf2(float a, float b) {
    __hip_bfloat162 h = __float22bfloat162_rn(make_float2(a, b));
    union { __hip_bfloat162 h; unsigned u; } c; c.h = h; return c.u;
}

// Block = 16 tokens, 8 waves, ONE barrier.
// Pre-barrier:  enc load (fused f32 passthrough) -> B-frags; C rows staged to LDS;
//               phase A S_ext[j][t] partials via MFMA with M read directly from L2
//               (K = 64 per wave); partials to spart.
// Post-barrier: reduce 8 slices, masked band softmax, in-lane p handoff to the
//               phase-B B-fragment (verified R10/R11), phase B from staged C.
__global__ __launch_bounds__(512)
void attn_cell_kernel(const int* __restrict__ symbols,
                      const float* __restrict__ encodings,
                      const float* __restrict__ M,
                      const float* __restrict__ C,
                      float* __restrict__ out,      // (B,T,1024)
                      float* __restrict__ p_out) {  // (B,T,16)
    __shared__ __align__(16) unsigned short cbuf[32 * C_LDW];  // 33280 B
    __shared__ __align__(16) float sp[8 * 16 * 36];            // 18432 B

    const int tid  = threadIdx.x;
    const int lane = tid & 63;
    const int w    = tid >> 6;      // 0..7
    const int q    = lane >> 4;     // 0..3
    const int t    = lane & 15;

    const int blk = blockIdx.x;
    const int b   = blk >> 7;
    const int t0  = (blk & 127) * 16;
    const int* symrow = symbols + b * T_;
    const size_t rowbase = (size_t)b * T_ + t0;

    // per-lane phase-A symbols: rows j = t and t+16
    int sa[2];
    #pragma unroll
    for (int g = 0; g < 2; ++g) {
        int pos = t0 + t + 16 * g - (LEFT_ - 1);
        pos = max(pos, 0); pos = min(pos, T_ - 1);
        sa[g] = symrow[pos];
    }

    // ---- enc load, fused exact-f32 passthrough, pack B-fragments ----
    FragU bf[2];
    {
        const float* ebase = encodings + (rowbase + t) * D_;
        float* obase = out + (rowbase + t) * 1024 + D_;
        #pragma unroll
        for (int kc = 0; kc < 2; ++kc) {
            const int d0 = 64 * w + 32 * kc + 4 * q;
            const float4 e0 = *(const float4*)(ebase + d0);
            const float4 e1 = *(const float4*)(ebase + d0 + 16);
            *(float4*)(obase + d0)      = e0;
            *(float4*)(obase + d0 + 16) = e1;
            bf[kc].u[0] = pack_bf2(e0.x, e0.y); bf[kc].u[1] = pack_bf2(e0.z, e0.w);
            bf[kc].u[2] = pack_bf2(e1.x, e1.y); bf[kc].u[3] = pack_bf2(e1.z, e1.w);
        }
    }

    // ---- stage C rows to LDS (independent of p; overlaps phase A) ----
    #pragma unroll
    for (int i = tid; i < 2048; i += 512) {
        const int j = i >> 6;
        const int g = i & 63;          // 16B source granule (8 f32)
        int pos = t0 - (LEFT_ - 1) + j;
        pos = max(pos, 0); pos = min(pos, T_ - 1);
        const float* src = C + (size_t)symrow[pos] * D_ + g * 8;
        const float4 v0 = ((const float4*)src)[0];
        const float4 v1 = ((const float4*)src)[1];
        u64* dst = (u64*)&cbuf[j * C_LDW + g * 8];
        dst[0] = (u64)pack_bf2(v0.x, v0.y) | ((u64)pack_bf2(v0.z, v0.w) << 32);
        dst[1] = (u64)pack_bf2(v1.x, v1.y) | ((u64)pack_bf2(v1.z, v1.w) << 32);
    }

    // ---- phase A: MFMA partials, M fragments straight from L2 (R10-verified) ----
    f32x4 acc0 = {0.f, 0.f, 0.f, 0.f}, acc1 = {0.f, 0.f, 0.f, 0.f};
    #pragma unroll
    for (int kc = 0; kc < 2; ++kc) {
        const int k0 = 64 * w + 32 * kc + 4 * q;
        {
            const float* ma = M + (size_t)sa[0] * D_ + k0;
            const float4 x0 = *(const float4*)ma;
            const float4 x1 = *(const float4*)(ma + 16);
            FragU af;
            af.u[0] = pack_bf2(x0.x, x0.y); af.u[1] = pack_bf2(x0.z, x0.w);
            af.u[2] = pack_bf2(x1.x, x1.y); af.u[3] = pack_bf2(x1.z, x1.w);
            acc0 = __builtin_amdgcn_mfma_f32_16x16x32_bf16(af.v, bf[kc].v, acc0, 0, 0, 0);
        }
        {
            const float* ma = M + (size_t)sa[1] * D_ + k0;
            const float4 x0 = *(const float4*)ma;
            const float4 x1 = *(const float4*)(ma + 16);
            FragU af;
            af.u[0] = pack_bf2(x0.x, x0.y); af.u[1] = pack_bf2(x0.z, x0.w);
            af.u[2] = pack_bf2(x1.x, x1.y); af.u[3] = pack_bf2(x1.z, x1.w);
            acc1 = __builtin_amdgcn_mfma_f32_16x16x32_bf16(af.v, bf[kc].v, acc1, 0, 0, 0);
        }
    }
    *(f32x4*)&sp[(w * 16 + t) * 36 + 4 * q]      = acc0;  // j = 4q+r
    *(f32x4*)&sp[(w * 16 + t) * 36 + 16 + 4 * q] = acc1;  // j = 16+4q+r

    __syncthreads();   // the only barrier

    // ---- reduce 8 slices; masked softmax; in-lane p handoff (R10/R11-verified) ----
    FragU pf;
    {
        f32x4 s0 = *(const f32x4*)&sp[t * 36 + 4 * q];
        f32x4 s1 = *(const f32x4*)&sp[t * 36 + 16 + 4 * q];
        #pragma unroll
        for (int w2 = 1; w2 < 8; ++w2) {
            s0 += *(const f32x4*)&sp[(w2 * 16 + t) * 36 + 4 * q];
            s1 += *(const f32x4*)&sp[(w2 * 16 + t) * 36 + 16 + 4 * q];
        }
        float mx = -3.0e38f;
        #pragma unroll
        for (int r = 0; r < 4; ++r) {
            if ((unsigned)(4 * q + r - t) < 16u)      mx = fmaxf(mx, s0[r]);
            if ((unsigned)(4 * q + r + 16 - t) < 16u) mx = fmaxf(mx, s1[r]);
        }
        mx = fmaxf(mx, __shfl_xor(mx, 16));
        mx = fmaxf(mx, __shfl_xor(mx, 32));
        float p0[4], p1[4];
        float sum = 0.f;
        #pragma unroll
        for (int r = 0; r < 4; ++r) {
            const bool m0 = (unsigned)(4 * q + r - t) < 16u;
            const bool m1 = (unsigned)(4 * q + r + 16 - t) < 16u;
            p0[r] = m0 ? __expf(s0[r] - mx) : 0.f;
            p1[r] = m1 ? __expf(s1[r] - mx) : 0.f;
            sum += p0[r] + p1[r];
        }
        sum += __shfl_xor(sum, 16);
        sum += __shfl_xor(sum, 32);
        const float inv = 1.f / sum;
        #pragma unroll
        for (int r = 0; r < 4; ++r) { p0[r] *= inv; p1[r] *= inv; }

        if (w == 0) {
            #pragma unroll
            for (int r = 0; r < 4; ++r) {
                const int j0 = 4 * q + r;
                if ((unsigned)(j0 - t) < 16u)
                    p_out[(rowbase + t) * 16 + (j0 - t)] = p0[r];
                else
                    p_out[(rowbase + t) * 16 + (j0 + 16 - t)] = p1[r];
            }
        }
        pf.u[0] = pack_bf2(p0[0], p0[1]); pf.u[1] = pack_bf2(p0[2], p0[3]);
        pf.u[2] = pack_bf2(p1[0], p1[1]); pf.u[3] = pack_bf2(p1[2], p1[3]);
    }

    // ---- phase B: O^T tile = C^T · P^T from staged C (R11-verified) ----
    {
        #pragma unroll
        for (int m = 0; m < 4; ++m) {
            const int dc = w * 4 + m;           // d-chunk 0..31
            const int dA = dc * 16 + t;
            unsigned short cbits[8];
            #pragma unroll
            for (int e = 0; e < 8; ++e) {
                const int j = 4 * q + (e & 3) + 16 * (e >> 2);
                cbits[e] = cbuf[j * C_LDW + dA];
            }
            FragU af;
            af.u[0] = cbits[0] | ((unsigned)cbits[1] << 16);
            af.u[1] = cbits[2] | ((unsigned)cbits[3] << 16);
            af.u[2] = cbits[4] | ((unsigned)cbits[5] << 16);
            af.u[3] = cbits[6] | ((unsigned)cbits[7] << 16);
            f32x4 o = {0.f, 0.f, 0.f, 0.f};
            o = __builtin_amdgcn_mfma_f32_16x16x32_bf16(af.v, pf.v, o, 0, 0, 0);
            float* ob = out + (rowbase + t) * 1024 + dc * 16 + 4 * q;
            *(float4*)ob = make_float4(o[0], o[1], o[2], o[3]);
        }
    }
}

extern "C" void kernel_launch(void* const* d_in, const int* in_sizes, int n_in,
                              void* d_out, int out_size, void* d_ws, size_t ws_size,
                              hipStream_t stream) {
    const int*   symbols   = (const int*)d_in[0];
    const float* encodings = (const float*)d_in[1];
    const float* M         = (const float*)d_in[2];
    const float* C         = (const float*)d_in[3];
    float* out   = (float*)d_out;
    float* p_out = out + (size_t)B_ * T_ * 1024;   // concat order: output, then p

    dim3 grid(B_ * (T_ / 16));                     // 1024 blocks x 512 threads
    attn_cell_kernel<<<grid, 512, 0, stream>>>(symbols, encodings, M, C, out, p_out);
}